// Round 11
// baseline (2872.527 us; speedup 1.0000x reference)
//
// R20: two co-resident exchange chains per XCD. Step model (R10/R12/R16 fit):
// 7.4us = compute 1.4 + gather ~1.4 + publish->flag->poll chain ~3.6 (skew-
// dominated). R13's serial phase-stagger couldn't overlap (WG blocks on A's
// poll before B's work). Fix: TRUE concurrency — split each 4-sample group
// into two independent 2-sample groups; each XCD hosts 2 groups x 32 WGs =
// 2 WGs/CU (one per chain). When A-waves stall on poll/gather vmcnt, B-waves
// issue FMAs on the same SIMDs. Feasible: VGPR=256 exactly -> 8 waves/CU
// (m69) = 2x4-wave WGs; register pressure DROPS vs R12 (acc[9][4]->[9][2]);
// LDS ~7KB/WG, occupancy pad removed (we want 2/CU now). Per-group protocol
// byte-identical R12: sc1 flag damper + valve, single sc1 gather proven by
// flag ordering, publish drained by barrier before tid0's flag store, prep
// seeds buf0 + zeroes flags. Per-group exchange halves (6KB, 384 req/WG).
// Fallback if VGPR>256: chains serialize (passes, slow) - maps the boundary.
// xg_gemm: R19's 128x128 tile (banked win). prep: 16-group layout.
#include <hip/hip_runtime.h>
#include <cstdint>
#include <cstddef>

#define H    768
#define G3   2304
#define TT   512
#define BS   32
#define NGRP 8
#define GWG  32        // worker WGs per group; 2 groups (64 WGs) per XCD
#define GRID_GRU 2048  // oversubscribed; ticket winners persist

// ctrl block inside xg dead zone (b=0, t>=384; L[0]~256 => never touched)
#define WS_XG    0
#define WS_CTRL  3538944                 // byte offset of xg[0][384][0]
#define CT_TICK  0                       // uint[8]
#define CT_FLAGS 64                      // uint[16][32] = 2048 B
#define CT_L     2112                    // int[32]
#define CT_HB    2240                    // float[16][2][1536] = 196608 B

typedef float vf4 __attribute__((ext_vector_type(4)));

// ---------------- phase 1: lengths + tickets/flags + hF buf0 seed -------------
__global__ void prep_kernel(const int* __restrict__ mask, const float* __restrict__ gc,
                            int* __restrict__ L, unsigned int* __restrict__ tick,
                            unsigned int* __restrict__ flags,
                            float* __restrict__ hF) {
    __shared__ int sbuf[256];
    const int b = blockIdx.x, tid = threadIdx.x;
    int c = 0;
    for (int t = tid; t < TT; t += 256) c += (mask[b * TT + t] != 0) ? 1 : 0;
    sbuf[tid] = c;
    __syncthreads();
    for (int off = 128; off > 0; off >>= 1) {
        if (tid < off) sbuf[tid] += sbuf[tid + off];
        __syncthreads();
    }
    if (tid == 0) {
        int l = sbuf[0];
        if (l < 1) l = 2;              // reference: where(L<1, 2, L)
        L[b] = l;
    }
    if (b == 0 && tid < NGRP) tick[tid] = 0u;
    if (tid < 16) flags[b * 16 + tid] = 0u;        // 32 blocks x 16 = 512
    // seed hF[gi][buf0][c*2+smp] = gc[c]: 16 gi x 1536 = 24576, 768 per block
    for (int i = tid; i < 768; i += 256) {
        const int e = b * 768 + i;                 // 0..24575
        const int gi = e / 1536, r = e - gi * 1536;
        hF[gi * 3072 + r] = gc[r >> 1];
    }
}

// ---------------- phase 2: xg = emb @ W_ih^T + b_ih — 128x128 tile (R19) ------
__global__ __launch_bounds__(256) void xg_gemm(
    const float* __restrict__ A, const float* __restrict__ W,
    const float* __restrict__ bih, const int* __restrict__ L,
    float* __restrict__ xg)
{
    const int mt = blockIdx.x, nt = blockIdx.y;
    const int b  = mt >> 2;              // 4 tiles of 128 rows per sample (512)
    const int t0 = (mt & 3) << 7;
    if (t0 >= L[b]) return;              // also protects the ctrl dead zone

    __shared__ __align__(16) float As[16][132];
    __shared__ __align__(16) float Ws[16][132];

    const int tid = threadIdx.x;
    const int m0 = mt << 7, n0 = nt << 7;
    const int lr = tid >> 2;
    const int lk = (tid & 3) << 2;
    const int tx = tid & 15, ty = tid >> 4;
    const int cx = tx << 2, cy = ty << 2;

    float c[8][8] = {};
    const float* Ap = A + (size_t)(m0 + lr) * H + lk;
    const float* Wp = W + (size_t)(n0 + lr) * H + lk;

    for (int k0 = 0; k0 < H; k0 += 16) {
        const float4 a0 = *(const float4*)(Ap + k0);
        const float4 a1 = *(const float4*)(Ap + (size_t)64 * H + k0);
        const float4 w0 = *(const float4*)(Wp + k0);
        const float4 w1 = *(const float4*)(Wp + (size_t)64 * H + k0);
        As[lk + 0][lr] = a0.x; As[lk + 1][lr] = a0.y;
        As[lk + 2][lr] = a0.z; As[lk + 3][lr] = a0.w;
        As[lk + 0][64 + lr] = a1.x; As[lk + 1][64 + lr] = a1.y;
        As[lk + 2][64 + lr] = a1.z; As[lk + 3][64 + lr] = a1.w;
        Ws[lk + 0][lr] = w0.x; Ws[lk + 1][lr] = w0.y;
        Ws[lk + 2][lr] = w0.z; Ws[lk + 3][lr] = w0.w;
        Ws[lk + 0][64 + lr] = w1.x; Ws[lk + 1][64 + lr] = w1.y;
        Ws[lk + 2][64 + lr] = w1.z; Ws[lk + 3][64 + lr] = w1.w;
        __syncthreads();
#pragma unroll
        for (int kk = 0; kk < 16; ++kk) {
            const float4 xa0 = *(const float4*)&As[kk][cy];
            const float4 xa1 = *(const float4*)&As[kk][64 + cy];
            const float4 xb0 = *(const float4*)&Ws[kk][cx];
            const float4 xb1 = *(const float4*)&Ws[kk][64 + cx];
            const float av[8] = {xa0.x, xa0.y, xa0.z, xa0.w,
                                 xa1.x, xa1.y, xa1.z, xa1.w};
            const float bv[8] = {xb0.x, xb0.y, xb0.z, xb0.w,
                                 xb1.x, xb1.y, xb1.z, xb1.w};
#pragma unroll
            for (int i = 0; i < 8; ++i)
#pragma unroll
                for (int j = 0; j < 8; ++j)
                    c[i][j] = fmaf(av[i], bv[j], c[i][j]);
        }
        __syncthreads();
    }
    const float4 bb0 = *(const float4*)&bih[n0 + cx];
    const float4 bb1 = *(const float4*)&bih[n0 + 64 + cx];
#pragma unroll
    for (int i = 0; i < 8; ++i) {
        const int r = m0 + ((i < 4) ? (cy + i) : (64 + cy + i - 4));
        float* cp = xg + (size_t)r * G3 + n0;
        float4 o0, o1;
        o0.x = c[i][0] + bb0.x; o0.y = c[i][1] + bb0.y;
        o0.z = c[i][2] + bb0.z; o0.w = c[i][3] + bb0.w;
        o1.x = c[i][4] + bb1.x; o1.y = c[i][5] + bb1.y;
        o1.z = c[i][6] + bb1.z; o1.w = c[i][7] + bb1.w;
        *(float4*)(cp + cx) = o0;
        *(float4*)(cp + 64 + cx) = o1;
    }
}

// -------- phase 3: per-XCD, 2 co-resident groups x 32 WGs, 2 samples each ----
__global__ __launch_bounds__(256, 1) void gru_kernel(
    const float* __restrict__ Whh, const float* __restrict__ bhh,
    const float* __restrict__ xg, const int* __restrict__ L,
    unsigned int* tick, unsigned int* flags, float* hF,
    float* __restrict__ out)
{
    unsigned int xcc;
    asm volatile("s_getreg_b32 %0, hwreg(HW_REG_XCC_ID)" : "=s"(xcc));
    const int g = (int)xcc;               // physical XCD 0..7

    __shared__ int s_wg;
    const int tid = threadIdx.x;
    if (tid == 0)
        s_wg = (int)__hip_atomic_fetch_add(&tick[g], 1u, __ATOMIC_RELAXED,
                                           __HIP_MEMORY_SCOPE_AGENT);
    __syncthreads();
    const int tkt = s_wg;
    if (tkt >= 2 * GWG) return;           // 64 workers per XCD (2 per CU)
    const int sub = tkt >> 5;             // chain 0 (samples 0,1) / 1 (2,3)
    const int wgl = tkt & 31;
    const int gi  = g * 2 + sub;          // group index 0..15

    __shared__ __align__(16) float h_lds[1536];    // [coord][smp0,smp1]
    __shared__ float sred[72 * 3];                 // [row][smp,pad]
    __shared__ int LsS[2];

    unsigned int* flagsg = flags + gi * GWG;
    float*        hFg    = hF + (size_t)gi * 3072;

    if (tid < 2) LsS[tid] = L[gi * 2 + tid];
    __syncthreads();
    const int S = max(LsS[0], LsS[1]);

    const int q = tid >> 5, kc = tid & 31;

    // weights -> VGPRs: w[j][ki] = Whh[row(q*9+j)][kc+32*ki]  (same as R12)
    float w[9][24];
#pragma unroll
    for (int j = 0; j < 9; ++j) {
        const int lr = q * 9 + j;
        const int row = (lr / 24) * H + 24 * wgl + (lr % 24);
        const float* wp = Whh + (size_t)row * H + kc;
#pragma unroll
        for (int ki = 0; ki < 24; ++ki) w[j][ki] = wp[ki << 5];
    }

    // gate-thread constants (tid<48: coord cg = 24*wgl + tid>>1, smp = tid&1)
    float bR = 0.f, bZ = 0.f, bN = 0.f;
    int Lb = 2, cg = 0, b = 0;
    const float* xb = xg;
    if (tid < 48) {
        cg = 24 * wgl + (tid >> 1);
        b  = gi * 2 + (tid & 1);
        bR = bhh[cg]; bZ = bhh[H + cg]; bN = bhh[2 * H + cg];
        Lb = LsS[tid & 1];
        xb = xg + (size_t)b * TT * G3 + cg;
    }

    for (int s = 0; s < S; ++s) {
        // ---- xg loads issued first: latency hides under the flag poll ----
        float xr = 0.f, xz = 0.f, xn = 0.f;
        if (tid < 48) {
            const int tt = (s < Lb) ? s : (Lb - 1);
            const float* xp = xb + (size_t)tt * G3;
            xr = xp[0]; xz = xp[H]; xn = xp[2 * H];
        }

        // ---- damper: wave0 polls this group's 32 flags >= s (sc1, proven) ----
        if (s && tid < 64) {
            const unsigned int* fp = flagsg + (tid & 31);
            int spins = 0;
            for (;;) {
                unsigned int v;
                asm volatile("global_load_dword %0, %1, off sc1\n\t"
                             "s_waitcnt vmcnt(0)"
                             : "=v"(v) : "v"(fp) : "memory");
                if (__all((int)v >= s)) break;
                if (((++spins) & 63) == 0) {      // belt-and-suspenders valve
                    v = __hip_atomic_load(fp, __ATOMIC_RELAXED,
                                          __HIP_MEMORY_SCOPE_AGENT);
                    if (__all((int)v >= s)) break;
                }
                if (spins > 4) __builtin_amdgcn_s_sleep(1);
            }
        }
        __syncthreads();

        // ---- gather 1536 f32: 192 threads x 2 dwordx4 (sc1), exactly once ----
        if (tid < 192) {
            const float* hr = hFg + (s & 1) * 1536 + 8 * tid;
            vf4 a0, a1;
            asm volatile(
                "global_load_dwordx4 %0, %2, off sc1\n\t"
                "global_load_dwordx4 %1, %2, off offset:16 sc1\n\t"
                "s_waitcnt vmcnt(0)"
                : "=&v"(a0), "=&v"(a1) : "v"(hr) : "memory");
            *(vf4*)&h_lds[8 * tid]     = a0;       // layout matches 1:1
            *(vf4*)&h_lds[8 * tid + 4] = a1;
        }
        __syncthreads();                               // syncA

        // hp read pulled before syncB (LDS rewritten only after next gather)
        float hp = 0.f;
        if (tid < 48) hp = h_lds[cg * 2 + (tid & 1)];

        // ---- dot: 24 x (ds_read_b64 + 18 fma) ----
        float acc[9][2] = {};
#pragma unroll
        for (int ki = 0; ki < 24; ++ki) {
            const float2 h2 = *(const float2*)&h_lds[(kc + (ki << 5)) * 2];
#pragma unroll
            for (int j = 0; j < 9; ++j) {
                const float wv = w[j][ki];
                acc[j][0] = fmaf(wv, h2.x, acc[j][0]);
                acc[j][1] = fmaf(wv, h2.y, acc[j][1]);
            }
        }
        // ---- reduce over kc (xor 1..16 stays in 32-lane half) ----
#pragma unroll
        for (int j = 0; j < 9; ++j)
#pragma unroll
            for (int m = 0; m < 2; ++m) {
                float x = acc[j][m];
                x += __shfl_xor(x, 1);
                x += __shfl_xor(x, 2);
                x += __shfl_xor(x, 4);
                x += __shfl_xor(x, 8);
                x += __shfl_xor(x, 16);
                acc[j][m] = x;
            }
        if (kc == 0) {
#pragma unroll
            for (int j = 0; j < 9; ++j) {
                sred[(q * 9 + j) * 3 + 0] = acc[j][0];
                sred[(q * 9 + j) * 3 + 1] = acc[j][1];
            }
        }
        __syncthreads();                               // syncB

        // ---- gates + publish (plain f32 workgroup-scope stores: L2-resident)
        float* hw = hFg + ((s + 1) & 1) * 1536;
        if (tid < 48) {
            const int c = tid >> 1, smp = tid & 1;
            const float sr = sred[(c) * 3 + smp]      + bR;
            const float sz = sred[(24 + c) * 3 + smp] + bZ;
            const float sn = sred[(48 + c) * 3 + smp] + bN;
            const float rg = 1.f / (1.f + expf(-(xr + sr)));
            const float zg = 1.f / (1.f + expf(-(xz + sz)));
            const float ng = tanhf(xn + rg * sn);
            const float hn = (s < Lb) ? ((1.f - zg) * ng + zg * hp) : hp;
            __hip_atomic_store(&hw[cg * 2 + smp], hn, __ATOMIC_RELAXED,
                               __HIP_MEMORY_SCOPE_WORKGROUP);
            if (s == Lb - 1) {
                out[b * H + cg] = hn;                     // outputs[b]
                if (b == BS - 1) out[BS * H + cg] = hn;   // hF == outputs[31]
            }
        }
        __syncthreads();    // drains publish stores (vmcnt(0) before s_barrier)
        if (tid == 0)
            __hip_atomic_store(&flagsg[wgl], (unsigned int)(s + 1),
                               __ATOMIC_RELAXED, __HIP_MEMORY_SCOPE_WORKGROUP);
    }
}

extern "C" void kernel_launch(void* const* d_in, const int* in_sizes, int n_in,
                              void* d_out, int out_size, void* d_ws, size_t ws_size,
                              hipStream_t stream) {
    const float* emb  = (const float*)d_in[0];   // [32][512][768]
    const int*   mask = (const int*)d_in[1];     // [32][512]
    const float* gctx = (const float*)d_in[2];   // [1][1][768]
    const float* Wih  = (const float*)d_in[3];   // [2304][768]
    const float* Whh  = (const float*)d_in[4];   // [2304][768]
    const float* bih  = (const float*)d_in[5];   // [2304]
    const float* bhh  = (const float*)d_in[6];   // [2304]
    float* out = (float*)d_out;                  // 32*768 + 768 floats

    char* ws = (char*)d_ws;
    float*              xg    = (float*)(ws + WS_XG);
    char*               ctrl  = ws + WS_CTRL;
    unsigned int*       tick  = (unsigned int*)(ctrl + CT_TICK);
    unsigned int*       flags = (unsigned int*)(ctrl + CT_FLAGS);
    int*                L     = (int*)(ctrl + CT_L);
    float*              hF    = (float*)(ctrl + CT_HB);

    prep_kernel<<<BS, 256, 0, stream>>>(mask, gctx, L, tick, flags, hF);
    xg_gemm<<<dim3(128, 18), 256, 0, stream>>>(emb, Wih, bih, L, xg);
    gru_kernel<<<GRID_GRU, 256, 0, stream>>>(Whh, bhh, xg, L, tick, flags, hF, out);
}